// Round 8
// baseline (445.021 us; speedup 1.0000x reference)
//
#include <hip/hip_runtime.h>

#define NX_  8192
#define NF_  8192
#define DQ_  128
#define OUT_ 256
#define FS_  512

typedef float  f32x4  __attribute__((ext_vector_type(4)));
typedef short  bf16x8 __attribute__((ext_vector_type(8)));

static __device__ __forceinline__ void nt_store4(const float4& w, float* p) {
  f32x4 v; v.x = w.x; v.y = w.y; v.z = w.z; v.w = w.w;
  __builtin_nontemporal_store(v, (f32x4*)p);
}
static __device__ __forceinline__ ushort f2bf(float f) {   // RNE bf16
  union { float f; uint u; } c; c.f = f;
  uint r = c.u + 0x7FFF + ((c.u >> 16) & 1);
  return (ushort)(r >> 16);
}
static __device__ __forceinline__ float bf2f(ushort u) {
  union { uint u; float f; } c; c.u = ((uint)u) << 16; return c.f;
}

// ---------------------------------------------------------------------------
// Graph ranges: rng[0..16] = row starts (x_batch), rng[17..33] = key starts.
// ---------------------------------------------------------------------------
__global__ void ranges_kernel(const int* __restrict__ xb, const int* __restrict__ fb,
                              int* __restrict__ rng) {
  int t = threadIdx.x;
  if (t < 17) {
    int lo = 0, hi = NX_;
    while (lo < hi) { int mid = (lo + hi) >> 1; if (xb[mid] < t) lo = mid + 1; else hi = mid; }
    rng[t] = lo;
  } else if (t < 34) {
    int g = t - 17;
    int lo = 0, hi = NF_;
    while (lo < hi) { int mid = (lo + hi) >> 1; if (fb[mid] < g) lo = mid + 1; else hi = mid; }
    rng[17 + g] = lo;
  }
}

// ---------------------------------------------------------------------------
// Zero the whole attn output (268 MB) as a branchless max-BW stream.
// fused_attn later overwrites only the per-graph windows (~25 MB).
// ---------------------------------------------------------------------------
__global__ __launch_bounds__(256) void zero_attn(float* __restrict__ attn) {
  const size_t n4 = (size_t)NX_ * NF_ / 4;
  size_t stride = (size_t)gridDim.x * 256;
  float4 z = make_float4(0.f, 0.f, 0.f, 0.f);
  for (size_t i = (size_t)blockIdx.x * 256 + threadIdx.x; i < n4; i += stride)
    nt_store4(z, attn + (i << 2));
}

// ---------------------------------------------------------------------------
// Weight prep: split each W[k][n] into hi/lo bf16, stored transposed [n][k].
// ---------------------------------------------------------------------------
__global__ __launch_bounds__(256) void wprep_kernel(const float* __restrict__ Wh,
                                                    const float* __restrict__ Wk,
                                                    const float* __restrict__ Wv,
                                                    ushort* __restrict__ WhTh, ushort* __restrict__ WhTl,
                                                    ushort* __restrict__ WkTh, ushort* __restrict__ WkTl,
                                                    ushort* __restrict__ WvTh, ushort* __restrict__ WvTl) {
  int idx = blockIdx.x * 256 + threadIdx.x;
  float w; ushort* ph; ushort* pl; int off;
  if (idx < 32768) {                 // WhT [128][256]
    int n = idx >> 8, k = idx & 255;
    w = Wh[k * DQ_ + n]; ph = WhTh; pl = WhTl; off = idx;
  } else if (idx < 98304) {          // WkT [128][512]
    int i = idx - 32768; int n = i >> 9, k = i & 511;
    w = Wk[k * DQ_ + n]; ph = WkTh; pl = WkTl; off = i;
  } else if (idx < 229376) {         // WvT [256][512]
    int i = idx - 98304; int n = i >> 9, k = i & 511;
    w = Wv[k * OUT_ + n]; ph = WvTh; pl = WvTl; off = i;
  } else return;
  ushort hi = f2bf(w);
  ph[off] = hi;
  pl[off] = f2bf(w - bf2f(hi));
}

// ---------------------------------------------------------------------------
// Activation prep: split f[8192][512], h[8192][256] into bf16 hi/lo ONCE.
// ---------------------------------------------------------------------------
__global__ __launch_bounds__(256) void prep_split(const float* __restrict__ f,
                                                  const float* __restrict__ h,
                                                  ushort* __restrict__ fh, ushort* __restrict__ fl,
                                                  ushort* __restrict__ hh, ushort* __restrict__ hl) {
  const int NF4 = (NF_ * FS_) / 4;   // 1048576
  const int NH4 = (NX_ * OUT_) / 4;  // 524288
  int stride = gridDim.x * 256;
  for (int i = blockIdx.x * 256 + threadIdx.x; i < NF4 + NH4; i += stride) {
    const float4* src; ushort* ph; ushort* pl; int j;
    if (i < NF4) { src = (const float4*)f; ph = fh; pl = fl; j = i; }
    else         { src = (const float4*)h; ph = hh; pl = hl; j = i - NF4; }
    float4 v = src[j];
    ushort4 uh, ul;
    uh.x = f2bf(v.x); ul.x = f2bf(v.x - bf2f(uh.x));
    uh.y = f2bf(v.y); ul.y = f2bf(v.y - bf2f(uh.y));
    uh.z = f2bf(v.z); ul.z = f2bf(v.z - bf2f(uh.z));
    uh.w = f2bf(v.w); ul.w = f2bf(v.w - bf2f(uh.w));
    ((ushort4*)ph)[j] = uh;
    ((ushort4*)pl)[j] = ul;
  }
}

// ---------------------------------------------------------------------------
// MFMA projections, one launch (1024 blocks):
//   bid   0..255 : Q  = h @ Wh  -> Qh/Ql bf16 [8192][128]   (3-pass split)
//   bid 256..511 : K  = f @ Wk  -> Kh/Kl bf16 [8192][128]   (3-pass split)
//   bid 512..1023: VT = (f @ Wv)^T -> bf16 [256][8192]      (1-pass bf16:
//     V feeds a bf16 PV product; quantization there already ~2^-8.5)
// 64x64 tile, BK=64, 4 waves.
// ---------------------------------------------------------------------------
__global__ __launch_bounds__(256) void gemm_all(const ushort* __restrict__ fh, const ushort* __restrict__ fl,
                                                const ushort* __restrict__ hh, const ushort* __restrict__ hl,
                                                const ushort* __restrict__ WhTh, const ushort* __restrict__ WhTl,
                                                const ushort* __restrict__ WkTh, const ushort* __restrict__ WkTl,
                                                const ushort* __restrict__ WvTh,
                                                ushort* __restrict__ Qh, ushort* __restrict__ Ql,
                                                ushort* __restrict__ Kh, ushort* __restrict__ Kl,
                                                ushort* __restrict__ VT) {
  __shared__ ushort Ahi[64][64], Alo[64][64];   // 16 KB
  __shared__ ushort Bhi[64][64], Blo[64][64];   // 16 KB
  int bid = blockIdx.x;
  const ushort *Ah, *Al, *BTh, *BTl;
  int N, K, lid, mode;
  if (bid < 256)      { Ah = hh; Al = hl; BTh = WhTh; BTl = WhTl; N = DQ_;  K = OUT_; mode = 0; lid = bid; }
  else if (bid < 512) { Ah = fh; Al = fl; BTh = WkTh; BTl = WkTl; N = DQ_;  K = FS_;  mode = 1; lid = bid - 256; }
  else                { Ah = fh; Al = fh; BTh = WvTh; BTl = WvTh; N = OUT_; K = FS_;  mode = 2; lid = bid - 512; }
  int nbn = N >> 6;
  int bm = (lid / nbn) << 6, bn = (lid % nbn) << 6;
  int tid = threadIdx.x, lane = tid & 63, w = tid >> 6;
  int srow = tid >> 2, skq = (tid & 3) << 4;       // staging: 4 thr/row, 16 bf16 each
  bool split = (mode < 2);                          // block-uniform
  f32x4 acc[4];
#pragma unroll
  for (int i = 0; i < 4; ++i) acc[i] = (f32x4){0.f, 0.f, 0.f, 0.f};

  for (int k0 = 0; k0 < K; k0 += 64) {
    size_t aoff = (size_t)(bm + srow) * K + k0 + skq;
    size_t boff = (size_t)(bn + srow) * K + k0 + skq;
#pragma unroll
    for (int j = 0; j < 2; ++j) {                  // 8 bf16 per uint4, pure copies
      int sk = (skq + (j << 3)) ^ ((srow & 7) << 3);
      *(uint4*)&Ahi[srow][sk] = *(const uint4*)(Ah + aoff + (j << 3));
      *(uint4*)&Bhi[srow][sk] = *(const uint4*)(BTh + boff + (j << 3));
      if (split) {
        *(uint4*)&Alo[srow][sk] = *(const uint4*)(Al + aoff + (j << 3));
        *(uint4*)&Blo[srow][sk] = *(const uint4*)(BTl + boff + (j << 3));
      }
    }
    __syncthreads();
#pragma unroll
    for (int step = 0; step < 2; ++step) {
      int kb = (step << 5) + ((lane >> 4) << 3);
      int brow = (w << 4) + (lane & 15);
      int bsk = kb ^ ((brow & 7) << 3);
      bf16x8 bh = *(const bf16x8*)&Bhi[brow][bsk];
#pragma unroll
      for (int i = 0; i < 4; ++i) {
        int ar = (i << 4) + (lane & 15);
        int ask = kb ^ ((ar & 7) << 3);
        bf16x8 ah = *(const bf16x8*)&Ahi[ar][ask];
        acc[i] = __builtin_amdgcn_mfma_f32_16x16x32_bf16(ah, bh, acc[i], 0, 0, 0);
        if (split) {
          bf16x8 bl = *(const bf16x8*)&Blo[brow][bsk];
          bf16x8 al = *(const bf16x8*)&Alo[ar][ask];
          acc[i] = __builtin_amdgcn_mfma_f32_16x16x32_bf16(al, bh, acc[i], 0, 0, 0);
          acc[i] = __builtin_amdgcn_mfma_f32_16x16x32_bf16(ah, bl, acc[i], 0, 0, 0);
        }
      }
    }
    __syncthreads();
  }
  int cr = (lane >> 4) << 2, cc = lane & 15;
  if (mode < 2) {
    ushort* Ch = (mode == 0) ? Qh : Kh;
    ushort* Cl = (mode == 0) ? Ql : Kl;
#pragma unroll
    for (int i = 0; i < 4; ++i)
#pragma unroll
      for (int r = 0; r < 4; ++r) {
        float v = acc[i][r];
        ushort hi = f2bf(v);
        size_t o = (size_t)(bm + (i << 4) + cr + r) * DQ_ + bn + (w << 4) + cc;
        Ch[o] = hi;
        Cl[o] = f2bf(v - bf2f(hi));
      }
  } else {
#pragma unroll
    for (int i = 0; i < 4; ++i) {                  // m consecutive in r -> 8B packs
      ushort4 o;
      o.x = f2bf(acc[i][0]); o.y = f2bf(acc[i][1]);
      o.z = f2bf(acc[i][2]); o.w = f2bf(acc[i][3]);
      *(ushort4*)&VT[(size_t)(bn + (w << 4) + cc) * NX_ + bm + (i << 4) + cr] = o;
    }
  }
}

// ---------------------------------------------------------------------------
// MFMA fused attention. Block = 16 query rows (grid 512), 4 waves.
// Scores: split-bf16 mfma(Q,K) per 16x16 key-tile (wave w owns tiles
// {w, w+4, ...}); softmax via 16-lane shfl_xor + LDS cross-wave combine;
// P -> LDS bf16; attn WINDOW-only nt-stores (zeros pre-laid by zero_attn);
// PV via mfma(P, VT).
// ---------------------------------------------------------------------------
__global__ __launch_bounds__(256) void fused_attn(const ushort* __restrict__ Qh, const ushort* __restrict__ Ql,
                                                  const ushort* __restrict__ Kh, const ushort* __restrict__ Kl,
                                                  const ushort* __restrict__ VT,
                                                  const int* __restrict__ xb,
                                                  const int* __restrict__ rng,
                                                  float* __restrict__ attn,
                                                  float* __restrict__ ctx) {
  __shared__ ushort Pb[16][784];     // bf16 probs, padded stride (25 KB)
  __shared__ float wred[8][16];      // [0..3]=per-wave row max, [4..7]=row sum
  int r0 = blockIdx.x << 4;
  int tid = threadIdx.x;
  int w = tid >> 6, lane = tid & 63;
  int lg = lane >> 4, li = lane & 15;
  int g0 = xb[r0], g1 = xb[r0 + 15];
  for (int g = g0; g <= g1; ++g) {
    int rs = rng[g], re = rng[g + 1];
    int ars = (rs > r0 ? rs : r0) - r0;
    int are = (re < r0 + 16 ? re : r0 + 16) - r0;
    if (ars >= are) continue;                 // block-uniform
    int ks = rng[17 + g], ke = rng[18 + g];
    int kbase = ks & ~7;                      // 16B-align bf16 frag reads
    // ---- Q fragments (all 4 d-blocks, hi+lo) ----
    const ushort* qrh = Qh + (size_t)(r0 + li) * DQ_ + (lg << 3);
    const ushort* qrl = Ql + (size_t)(r0 + li) * DQ_ + (lg << 3);
    bf16x8 qh[4], ql[4];
#pragma unroll
    for (int db = 0; db < 4; ++db) {
      qh[db] = *(const bf16x8*)(qrh + (db << 5));
      ql[db] = *(const bf16x8*)(qrl + (db << 5));
    }
    // ---- scores: 12 key-tiles per wave ----
    f32x4 s[12];
#pragma unroll
    for (int tt = 0; tt < 12; ++tt) {
      int key0 = kbase + (((tt << 2) + w) << 4);
      int krow = key0 + li; if (krow > NF_ - 1) krow = NF_ - 1;
      const ushort* krh = Kh + (size_t)krow * DQ_ + (lg << 3);
      const ushort* krl = Kl + (size_t)krow * DQ_ + (lg << 3);
      f32x4 a = (f32x4){0.f, 0.f, 0.f, 0.f};
#pragma unroll
      for (int db = 0; db < 4; ++db) {
        bf16x8 kh = *(const bf16x8*)(krh + (db << 5));
        bf16x8 kl = *(const bf16x8*)(krl + (db << 5));
        a = __builtin_amdgcn_mfma_f32_16x16x32_bf16(qh[db], kh, a, 0, 0, 0);
        a = __builtin_amdgcn_mfma_f32_16x16x32_bf16(ql[db], kh, a, 0, 0, 0);
        a = __builtin_amdgcn_mfma_f32_16x16x32_bf16(qh[db], kl, a, 0, 0, 0);
      }
      s[tt] = a;
    }
    // ---- softmax: row = lg*4 + r lives in lanes lg*16..lg*16+15 ----
    float pm[4];
#pragma unroll
    for (int r = 0; r < 4; ++r) pm[r] = -3.0e38f;
#pragma unroll
    for (int tt = 0; tt < 12; ++tt) {
      int col = kbase + (((tt << 2) + w) << 4) + li;
      bool valid = (col >= ks) && (col < ke);
#pragma unroll
      for (int r = 0; r < 4; ++r) pm[r] = fmaxf(pm[r], valid ? s[tt][r] : -3.0e38f);
    }
#pragma unroll
    for (int r = 0; r < 4; ++r) {
      pm[r] = fmaxf(pm[r], __shfl_xor(pm[r], 1));
      pm[r] = fmaxf(pm[r], __shfl_xor(pm[r], 2));
      pm[r] = fmaxf(pm[r], __shfl_xor(pm[r], 4));
      pm[r] = fmaxf(pm[r], __shfl_xor(pm[r], 8));
    }
    if (li == 0) {
#pragma unroll
      for (int r = 0; r < 4; ++r) wred[w][(lg << 2) + r] = pm[r];
    }
    __syncthreads();
    float m[4], ps[4];
#pragma unroll
    for (int r = 0; r < 4; ++r) {
      int row = (lg << 2) + r;
      m[r] = fmaxf(fmaxf(wred[0][row], wred[1][row]), fmaxf(wred[2][row], wred[3][row]));
      ps[r] = 0.f;
    }
#pragma unroll
    for (int tt = 0; tt < 12; ++tt) {
      int col = kbase + (((tt << 2) + w) << 4) + li;
      bool valid = (col >= ks) && (col < ke);
#pragma unroll
      for (int r = 0; r < 4; ++r) {
        float e = valid ? __expf(s[tt][r] - m[r]) : 0.f;
        s[tt][r] = e;
        ps[r] += e;
      }
    }
#pragma unroll
    for (int r = 0; r < 4; ++r) {
      ps[r] += __shfl_xor(ps[r], 1);
      ps[r] += __shfl_xor(ps[r], 2);
      ps[r] += __shfl_xor(ps[r], 4);
      ps[r] += __shfl_xor(ps[r], 8);
    }
    if (li == 0) {
#pragma unroll
      for (int r = 0; r < 4; ++r) wred[4 + w][(lg << 2) + r] = ps[r];
    }
    __syncthreads();
    float inv[4];
#pragma unroll
    for (int r = 0; r < 4; ++r) {
      int row = (lg << 2) + r;
      inv[r] = 1.0f / (wred[4][row] + wred[5][row] + wred[6][row] + wred[7][row]);
    }
    // ---- P -> LDS bf16 ----
#pragma unroll
    for (int tt = 0; tt < 12; ++tt) {
      int kc = (((tt << 2) + w) << 4) + li;
#pragma unroll
      for (int r = 0; r < 4; ++r)
        Pb[(lg << 2) + r][kc] = f2bf(s[tt][r] * inv[r]);
    }
    __syncthreads();
    // ---- attn WINDOW write (zeros already laid by zero_attn) ----
    for (int idx = tid; idx < 16 * 192; idx += 256) {     // 192 f4 per row
      int row = idx / 192;
      if (row < ars || row >= are) continue;
      int c4 = idx - row * 192;
      int col = kbase + (c4 << 2);
      if (col >= NF_) continue;
      ushort4 pu = *(const ushort4*)&Pb[row][c4 << 2];
      float4 wv;
      wv.x = bf2f(pu.x); wv.y = bf2f(pu.y); wv.z = bf2f(pu.z); wv.w = bf2f(pu.w);
      nt_store4(wv, attn + (size_t)(r0 + row) * NF_ + col);
    }
    // ---- PV: ctx = P @ V via MFMA; wave w owns out cols [w*64, w*64+64) ----
    int nsteps = (ke - kbase + 31) >> 5;
    f32x4 pacc[4];
#pragma unroll
    for (int ot = 0; ot < 4; ++ot) pacc[ot] = (f32x4){0.f, 0.f, 0.f, 0.f};
    for (int st = 0; st < nsteps; ++st) {
      bf16x8 pfr = *(const bf16x8*)&Pb[li][(st << 5) + (lg << 3)];
      int kaddr = kbase + (st << 5) + (lg << 3);
      if (kaddr > NF_ - 8) kaddr = NF_ - 8;           // clamp (P=0 there)
#pragma unroll
      for (int ot = 0; ot < 4; ++ot) {
        const ushort* vr = VT + (size_t)((w << 6) + (ot << 4) + li) * NX_ + kaddr;
        bf16x8 vfr = *(const bf16x8*)vr;
        pacc[ot] = __builtin_amdgcn_mfma_f32_16x16x32_bf16(pfr, vfr, pacc[ot], 0, 0, 0);
      }
    }
#pragma unroll
    for (int ot = 0; ot < 4; ++ot)
#pragma unroll
      for (int r = 0; r < 4; ++r) {
        int row = (lg << 2) + r;
        if (row >= ars && row < are)
          ctx[(size_t)(r0 + row) * OUT_ + (w << 6) + (ot << 4) + li] = pacc[ot][r];
      }
    __syncthreads();                     // Pb/wred reusable for next graph
  }
}

// ---------------------------------------------------------------------------
extern "C" void kernel_launch(void* const* d_in, const int* in_sizes, int n_in,
                              void* d_out, int out_size, void* d_ws, size_t ws_size,
                              hipStream_t stream) {
  const float* f   = (const float*)d_in[0];
  const float* h   = (const float*)d_in[2];
  const int*   fb  = (const int*)d_in[5];
  const int*   xbt = (const int*)d_in[6];
  const float* Wh  = (const float*)d_in[8];
  const float* Wk  = (const float*)d_in[9];
  const float* Wv  = (const float*)d_in[10];

  float* ctx_out  = (float*)d_out;                   // [8192][256]
  float* attn_out = ctx_out + (size_t)NX_ * OUT_;    // [8192][8192]

  ushort* fh   = (ushort*)d_ws;
  ushort* fl   = fh + (size_t)NF_ * FS_;
  ushort* hh   = fl + (size_t)NF_ * FS_;
  ushort* hl   = hh + (size_t)NX_ * OUT_;
  ushort* Qh   = hl + (size_t)NX_ * OUT_;
  ushort* Ql   = Qh + (size_t)NX_ * DQ_;
  ushort* Kh   = Ql + (size_t)NX_ * DQ_;
  ushort* Kl   = Kh + (size_t)NF_ * DQ_;
  ushort* VT   = Kl + (size_t)NF_ * DQ_;
  ushort* WhTh = VT + (size_t)OUT_ * NX_;
  ushort* WhTl = WhTh + 32768;
  ushort* WkTh = WhTl + 32768;
  ushort* WkTl = WkTh + 65536;
  ushort* WvTh = WkTl + 65536;
  ushort* WvTl = WvTh + 131072;
  int*    rng  = (int*)(WvTl + 131072);

  hipLaunchKernelGGL(ranges_kernel, dim3(1), dim3(64), 0, stream, xbt, fb, rng);
  hipLaunchKernelGGL(zero_attn, dim3(4096), dim3(256), 0, stream, attn_out);
  hipLaunchKernelGGL(wprep_kernel, dim3(896), dim3(256), 0, stream,
                     Wh, Wk, Wv, WhTh, WhTl, WkTh, WkTl, WvTh, WvTl);
  hipLaunchKernelGGL(prep_split, dim3(2048), dim3(256), 0, stream,
                     f, h, fh, fl, hh, hl);
  hipLaunchKernelGGL(gemm_all, dim3(1024), dim3(256), 0, stream,
                     fh, fl, hh, hl, WhTh, WhTl, WkTh, WkTl, WvTh,
                     Qh, Ql, Kh, Kl, VT);
  hipLaunchKernelGGL(fused_attn, dim3(NX_ / 16), dim3(256), 0, stream,
                     Qh, Ql, Kh, Kl, VT, xbt, rng, attn_out, ctx_out);
}

// Round 9
// 425.736 us; speedup vs baseline: 1.0453x; 1.0453x over previous
//
#include <hip/hip_runtime.h>

#define NX_  8192
#define NF_  8192
#define DQ_  128
#define OUT_ 256
#define FS_  512

typedef float  f32x4  __attribute__((ext_vector_type(4)));
typedef short  bf16x8 __attribute__((ext_vector_type(8)));

static __device__ __forceinline__ void nt_store4(const float4& w, float* p) {
  f32x4 v; v.x = w.x; v.y = w.y; v.z = w.z; v.w = w.w;
  __builtin_nontemporal_store(v, (f32x4*)p);
}
static __device__ __forceinline__ ushort f2bf(float f) {   // RNE bf16
  union { float f; uint u; } c; c.f = f;
  uint r = c.u + 0x7FFF + ((c.u >> 16) & 1);
  return (ushort)(r >> 16);
}
static __device__ __forceinline__ float bf2f(ushort u) {
  union { uint u; float f; } c; c.u = ((uint)u) << 16; return c.f;
}

// ---------------------------------------------------------------------------
// Graph ranges: rng[0..16] = row starts (x_batch), rng[17..33] = key starts.
// ---------------------------------------------------------------------------
__global__ void ranges_kernel(const int* __restrict__ xb, const int* __restrict__ fb,
                              int* __restrict__ rng) {
  int t = threadIdx.x;
  if (t < 17) {
    int lo = 0, hi = NX_;
    while (lo < hi) { int mid = (lo + hi) >> 1; if (xb[mid] < t) lo = mid + 1; else hi = mid; }
    rng[t] = lo;
  } else if (t < 34) {
    int g = t - 17;
    int lo = 0, hi = NF_;
    while (lo < hi) { int mid = (lo + hi) >> 1; if (fb[mid] < g) lo = mid + 1; else hi = mid; }
    rng[17 + g] = lo;
  }
}

// ---------------------------------------------------------------------------
// Weight prep: split each W[k][n] into hi/lo bf16, stored transposed [n][k].
// ---------------------------------------------------------------------------
__global__ __launch_bounds__(256) void wprep_kernel(const float* __restrict__ Wh,
                                                    const float* __restrict__ Wk,
                                                    const float* __restrict__ Wv,
                                                    ushort* __restrict__ WhTh, ushort* __restrict__ WhTl,
                                                    ushort* __restrict__ WkTh, ushort* __restrict__ WkTl,
                                                    ushort* __restrict__ WvTh, ushort* __restrict__ WvTl) {
  int idx = blockIdx.x * 256 + threadIdx.x;
  float w; ushort* ph; ushort* pl; int off;
  if (idx < 32768) {                 // WhT [128][256]
    int n = idx >> 8, k = idx & 255;
    w = Wh[k * DQ_ + n]; ph = WhTh; pl = WhTl; off = idx;
  } else if (idx < 98304) {          // WkT [128][512]
    int i = idx - 32768; int n = i >> 9, k = i & 511;
    w = Wk[k * DQ_ + n]; ph = WkTh; pl = WkTl; off = i;
  } else if (idx < 229376) {         // WvT [256][512]
    int i = idx - 98304; int n = i >> 9, k = i & 511;
    w = Wv[k * OUT_ + n]; ph = WvTh; pl = WvTl; off = i;
  } else return;
  ushort hi = f2bf(w);
  ph[off] = hi;
  pl[off] = f2bf(w - bf2f(hi));
}

// ---------------------------------------------------------------------------
// Activation prep: split f[8192][512], h[8192][256] into bf16 hi/lo ONCE.
// ---------------------------------------------------------------------------
__global__ __launch_bounds__(256) void prep_split(const float* __restrict__ f,
                                                  const float* __restrict__ h,
                                                  ushort* __restrict__ fh, ushort* __restrict__ fl,
                                                  ushort* __restrict__ hh, ushort* __restrict__ hl) {
  const int NF4 = (NF_ * FS_) / 4;   // 1048576
  const int NH4 = (NX_ * OUT_) / 4;  // 524288
  int stride = gridDim.x * 256;
  for (int i = blockIdx.x * 256 + threadIdx.x; i < NF4 + NH4; i += stride) {
    const float4* src; ushort* ph; ushort* pl; int j;
    if (i < NF4) { src = (const float4*)f; ph = fh; pl = fl; j = i; }
    else         { src = (const float4*)h; ph = hh; pl = hl; j = i - NF4; }
    float4 v = src[j];
    ushort4 uh, ul;
    uh.x = f2bf(v.x); ul.x = f2bf(v.x - bf2f(uh.x));
    uh.y = f2bf(v.y); ul.y = f2bf(v.y - bf2f(uh.y));
    uh.z = f2bf(v.z); ul.z = f2bf(v.z - bf2f(uh.z));
    uh.w = f2bf(v.w); ul.w = f2bf(v.w - bf2f(uh.w));
    ((ushort4*)ph)[j] = uh;
    ((ushort4*)pl)[j] = ul;
  }
}

// ---------------------------------------------------------------------------
// MFMA projections, one launch (1024 blocks):
//   bid   0..255 : Q  = h @ Wh  -> Qh/Ql bf16 [8192][128]   (3-pass split)
//   bid 256..511 : K  = f @ Wk  -> Kh/Kl bf16 [8192][128]   (3-pass split)
//   bid 512..1023: VT = (f @ Wv)^T -> bf16 [256][8192]      (1-pass bf16)
// 64x64 tile, BK=64, 4 waves.
// ---------------------------------------------------------------------------
__global__ __launch_bounds__(256) void gemm_all(const ushort* __restrict__ fh, const ushort* __restrict__ fl,
                                                const ushort* __restrict__ hh, const ushort* __restrict__ hl,
                                                const ushort* __restrict__ WhTh, const ushort* __restrict__ WhTl,
                                                const ushort* __restrict__ WkTh, const ushort* __restrict__ WkTl,
                                                const ushort* __restrict__ WvTh,
                                                ushort* __restrict__ Qh, ushort* __restrict__ Ql,
                                                ushort* __restrict__ Kh, ushort* __restrict__ Kl,
                                                ushort* __restrict__ VT) {
  __shared__ ushort Ahi[64][64], Alo[64][64];   // 16 KB
  __shared__ ushort Bhi[64][64], Blo[64][64];   // 16 KB
  int bid = blockIdx.x;
  const ushort *Ah, *Al, *BTh, *BTl;
  int N, K, lid, mode;
  if (bid < 256)      { Ah = hh; Al = hl; BTh = WhTh; BTl = WhTl; N = DQ_;  K = OUT_; mode = 0; lid = bid; }
  else if (bid < 512) { Ah = fh; Al = fl; BTh = WkTh; BTl = WkTl; N = DQ_;  K = FS_;  mode = 1; lid = bid - 256; }
  else                { Ah = fh; Al = fh; BTh = WvTh; BTl = WvTh; N = OUT_; K = FS_;  mode = 2; lid = bid - 512; }
  int nbn = N >> 6;
  int bm = (lid / nbn) << 6, bn = (lid % nbn) << 6;
  int tid = threadIdx.x, lane = tid & 63, w = tid >> 6;
  int srow = tid >> 2, skq = (tid & 3) << 4;       // staging: 4 thr/row, 16 bf16 each
  bool split = (mode < 2);                          // block-uniform
  f32x4 acc[4];
#pragma unroll
  for (int i = 0; i < 4; ++i) acc[i] = (f32x4){0.f, 0.f, 0.f, 0.f};

  for (int k0 = 0; k0 < K; k0 += 64) {
    size_t aoff = (size_t)(bm + srow) * K + k0 + skq;
    size_t boff = (size_t)(bn + srow) * K + k0 + skq;
#pragma unroll
    for (int j = 0; j < 2; ++j) {                  // 8 bf16 per uint4, pure copies
      int sk = (skq + (j << 3)) ^ ((srow & 7) << 3);
      *(uint4*)&Ahi[srow][sk] = *(const uint4*)(Ah + aoff + (j << 3));
      *(uint4*)&Bhi[srow][sk] = *(const uint4*)(BTh + boff + (j << 3));
      if (split) {
        *(uint4*)&Alo[srow][sk] = *(const uint4*)(Al + aoff + (j << 3));
        *(uint4*)&Blo[srow][sk] = *(const uint4*)(BTl + boff + (j << 3));
      }
    }
    __syncthreads();
#pragma unroll
    for (int step = 0; step < 2; ++step) {
      int kb = (step << 5) + ((lane >> 4) << 3);
      int brow = (w << 4) + (lane & 15);
      int bsk = kb ^ ((brow & 7) << 3);
      bf16x8 bh = *(const bf16x8*)&Bhi[brow][bsk];
#pragma unroll
      for (int i = 0; i < 4; ++i) {
        int ar = (i << 4) + (lane & 15);
        int ask = kb ^ ((ar & 7) << 3);
        bf16x8 ah = *(const bf16x8*)&Ahi[ar][ask];
        acc[i] = __builtin_amdgcn_mfma_f32_16x16x32_bf16(ah, bh, acc[i], 0, 0, 0);
        if (split) {
          bf16x8 bl = *(const bf16x8*)&Blo[brow][bsk];
          bf16x8 al = *(const bf16x8*)&Alo[ar][ask];
          acc[i] = __builtin_amdgcn_mfma_f32_16x16x32_bf16(al, bh, acc[i], 0, 0, 0);
          acc[i] = __builtin_amdgcn_mfma_f32_16x16x32_bf16(ah, bl, acc[i], 0, 0, 0);
        }
      }
    }
    __syncthreads();
  }
  int cr = (lane >> 4) << 2, cc = lane & 15;
  if (mode < 2) {
    ushort* Ch = (mode == 0) ? Qh : Kh;
    ushort* Cl = (mode == 0) ? Ql : Kl;
#pragma unroll
    for (int i = 0; i < 4; ++i)
#pragma unroll
      for (int r = 0; r < 4; ++r) {
        float v = acc[i][r];
        ushort hi = f2bf(v);
        size_t o = (size_t)(bm + (i << 4) + cr + r) * DQ_ + bn + (w << 4) + cc;
        Ch[o] = hi;
        Cl[o] = f2bf(v - bf2f(hi));
      }
  } else {
#pragma unroll
    for (int i = 0; i < 4; ++i) {                  // m consecutive -> 8B packs
      ushort4 o;
      o.x = f2bf(acc[i][0]); o.y = f2bf(acc[i][1]);
      o.z = f2bf(acc[i][2]); o.w = f2bf(acc[i][3]);
      *(ushort4*)&VT[(size_t)(bn + (w << 4) + cc) * NX_ + bm + (i << 4) + cr] = o;
    }
  }
}

// ---------------------------------------------------------------------------
// MFMA fused attention. Block = 16 query rows, 512 threads = 8 waves.
// Each wave owns 6 key-tiles (s[6] -> low VGPR -> ~4 waves/SIMD occupancy).
// XCD-chunked block swizzle keeps a graph's K window in one XCD's L2.
// Full attn rows written here (window from LDS, zeros elsewhere) -- no
// separate zero pass (round-8 lesson: split zeroing cost +25us net).
// ---------------------------------------------------------------------------
__global__ __launch_bounds__(512) void fused_attn(const ushort* __restrict__ Qh, const ushort* __restrict__ Ql,
                                                  const ushort* __restrict__ Kh, const ushort* __restrict__ Kl,
                                                  const ushort* __restrict__ VT,
                                                  const int* __restrict__ xb,
                                                  const int* __restrict__ rng,
                                                  float* __restrict__ attn,
                                                  float* __restrict__ ctx) {
  __shared__ ushort Pb[16][784];     // bf16 probs, padded stride (25 KB)
  __shared__ float wred[16][16];     // [0..7]=per-wave row max, [8..15]=row sum
  int bid = blockIdx.x;
  int sb = ((bid & 7) << 6) | (bid >> 3);   // XCD-chunked swizzle (512 = 8*64)
  int r0 = sb << 4;
  int tid = threadIdx.x;
  int w = tid >> 6, lane = tid & 63;
  int lg = lane >> 4, li = lane & 15;
  // ---- Q fragments: graph-independent, hoisted ----
  const ushort* qrh = Qh + (size_t)(r0 + li) * DQ_ + (lg << 3);
  const ushort* qrl = Ql + (size_t)(r0 + li) * DQ_ + (lg << 3);
  bf16x8 qh[4], ql[4];
#pragma unroll
  for (int db = 0; db < 4; ++db) {
    qh[db] = *(const bf16x8*)(qrh + (db << 5));
    ql[db] = *(const bf16x8*)(qrl + (db << 5));
  }
  int g0 = xb[r0], g1 = xb[r0 + 15];
  for (int g = g0; g <= g1; ++g) {
    int rs = rng[g], re = rng[g + 1];
    int ars = (rs > r0 ? rs : r0) - r0;
    int are = (re < r0 + 16 ? re : r0 + 16) - r0;
    if (ars >= are) continue;                 // block-uniform
    int ks = rng[17 + g], ke = rng[18 + g];
    int kbase = ks & ~7;                      // 16B-align bf16 frag reads
    // ---- scores: 6 key-tiles per wave (tile = tt*8 + w) ----
    f32x4 s[6];
#pragma unroll
    for (int tt = 0; tt < 6; ++tt) {
      int key0 = kbase + (((tt << 3) + w) << 4);
      int krow = key0 + li; if (krow > NF_ - 1) krow = NF_ - 1;
      const ushort* krh = Kh + (size_t)krow * DQ_ + (lg << 3);
      const ushort* krl = Kl + (size_t)krow * DQ_ + (lg << 3);
      f32x4 a = (f32x4){0.f, 0.f, 0.f, 0.f};
#pragma unroll
      for (int db = 0; db < 4; ++db) {
        bf16x8 kh = *(const bf16x8*)(krh + (db << 5));
        bf16x8 kl = *(const bf16x8*)(krl + (db << 5));
        a = __builtin_amdgcn_mfma_f32_16x16x32_bf16(qh[db], kh, a, 0, 0, 0);
        a = __builtin_amdgcn_mfma_f32_16x16x32_bf16(ql[db], kh, a, 0, 0, 0);
        a = __builtin_amdgcn_mfma_f32_16x16x32_bf16(qh[db], kl, a, 0, 0, 0);
      }
      s[tt] = a;
    }
    // ---- softmax: row = lg*4+r lives in lanes lg*16..lg*16+15 of each wave --
    float pm[4];
#pragma unroll
    for (int r = 0; r < 4; ++r) pm[r] = -3.0e38f;
#pragma unroll
    for (int tt = 0; tt < 6; ++tt) {
      int col = kbase + (((tt << 3) + w) << 4) + li;
      bool valid = (col >= ks) && (col < ke);
#pragma unroll
      for (int r = 0; r < 4; ++r) pm[r] = fmaxf(pm[r], valid ? s[tt][r] : -3.0e38f);
    }
#pragma unroll
    for (int r = 0; r < 4; ++r) {
      pm[r] = fmaxf(pm[r], __shfl_xor(pm[r], 1));
      pm[r] = fmaxf(pm[r], __shfl_xor(pm[r], 2));
      pm[r] = fmaxf(pm[r], __shfl_xor(pm[r], 4));
      pm[r] = fmaxf(pm[r], __shfl_xor(pm[r], 8));
    }
    if (li == 0) {
#pragma unroll
      for (int r = 0; r < 4; ++r) wred[w][(lg << 2) + r] = pm[r];
    }
    __syncthreads();
    float m[4], ps[4];
#pragma unroll
    for (int r = 0; r < 4; ++r) {
      int row = (lg << 2) + r;
      float m01 = fmaxf(wred[0][row], wred[1][row]);
      float m23 = fmaxf(wred[2][row], wred[3][row]);
      float m45 = fmaxf(wred[4][row], wred[5][row]);
      float m67 = fmaxf(wred[6][row], wred[7][row]);
      m[r] = fmaxf(fmaxf(m01, m23), fmaxf(m45, m67));
      ps[r] = 0.f;
    }
#pragma unroll
    for (int tt = 0; tt < 6; ++tt) {
      int col = kbase + (((tt << 3) + w) << 4) + li;
      bool valid = (col >= ks) && (col < ke);
#pragma unroll
      for (int r = 0; r < 4; ++r) {
        float e = valid ? __expf(s[tt][r] - m[r]) : 0.f;
        s[tt][r] = e;
        ps[r] += e;
      }
    }
#pragma unroll
    for (int r = 0; r < 4; ++r) {
      ps[r] += __shfl_xor(ps[r], 1);
      ps[r] += __shfl_xor(ps[r], 2);
      ps[r] += __shfl_xor(ps[r], 4);
      ps[r] += __shfl_xor(ps[r], 8);
    }
    if (li == 0) {
#pragma unroll
      for (int r = 0; r < 4; ++r) wred[8 + w][(lg << 2) + r] = ps[r];
    }
    __syncthreads();
    float inv[4];
#pragma unroll
    for (int r = 0; r < 4; ++r) {
      int row = (lg << 2) + r;
      float s0 = wred[8][row] + wred[9][row] + wred[10][row] + wred[11][row];
      float s1 = wred[12][row] + wred[13][row] + wred[14][row] + wred[15][row];
      inv[r] = 1.0f / (s0 + s1);
    }
    // ---- P -> LDS bf16 ----
#pragma unroll
    for (int tt = 0; tt < 6; ++tt) {
      int kc = (((tt << 3) + w) << 4) + li;
#pragma unroll
      for (int r = 0; r < 4; ++r)
        Pb[(lg << 2) + r][kc] = f2bf(s[tt][r] * inv[r]);
    }
    __syncthreads();
    // ---- attn write: full rows (window from Pb + zeros), nt f4 stores ----
    for (int idx = tid; idx < 16 * (NF_ / 4); idx += 512) {
      int row = idx >> 11;
      if (row < ars || row >= are) continue;
      int col = (idx & 2047) << 2;
      float4 wv = make_float4(0.f, 0.f, 0.f, 0.f);
      int rel = col - kbase;
      if (rel >= 0 && rel < 768) {
        ushort4 pu = *(const ushort4*)&Pb[row][rel];
        wv.x = bf2f(pu.x); wv.y = bf2f(pu.y); wv.z = bf2f(pu.z); wv.w = bf2f(pu.w);
      }
      nt_store4(wv, attn + (size_t)(r0 + row) * NF_ + col);
    }
    // ---- PV: ctx = P @ V via MFMA; wave w owns out cols [w*32, w*32+32) ----
    int nsteps = (ke - kbase + 31) >> 5;
    f32x4 pacc[2];
#pragma unroll
    for (int ot = 0; ot < 2; ++ot) pacc[ot] = (f32x4){0.f, 0.f, 0.f, 0.f};
    for (int st = 0; st < nsteps; ++st) {
      bf16x8 pfr = *(const bf16x8*)&Pb[li][(st << 5) + (lg << 3)];
      int kaddr = kbase + (st << 5) + (lg << 3);
      if (kaddr > NF_ - 8) kaddr = NF_ - 8;           // clamp (P=0 there)
#pragma unroll
      for (int ot = 0; ot < 2; ++ot) {
        const ushort* vr = VT + (size_t)((w << 5) + (ot << 4) + li) * NX_ + kaddr;
        bf16x8 vfr = *(const bf16x8*)vr;
        pacc[ot] = __builtin_amdgcn_mfma_f32_16x16x32_bf16(pfr, vfr, pacc[ot], 0, 0, 0);
      }
    }
#pragma unroll
    for (int ot = 0; ot < 2; ++ot)
#pragma unroll
      for (int r = 0; r < 4; ++r) {
        int row = (lg << 2) + r;
        if (row >= ars && row < are)
          ctx[(size_t)(r0 + row) * OUT_ + (w << 5) + (ot << 4) + li] = pacc[ot][r];
      }
    __syncthreads();                     // Pb/wred reusable for next graph
  }
}

// ---------------------------------------------------------------------------
extern "C" void kernel_launch(void* const* d_in, const int* in_sizes, int n_in,
                              void* d_out, int out_size, void* d_ws, size_t ws_size,
                              hipStream_t stream) {
  const float* f   = (const float*)d_in[0];
  const float* h   = (const float*)d_in[2];
  const int*   fb  = (const int*)d_in[5];
  const int*   xbt = (const int*)d_in[6];
  const float* Wh  = (const float*)d_in[8];
  const float* Wk  = (const float*)d_in[9];
  const float* Wv  = (const float*)d_in[10];

  float* ctx_out  = (float*)d_out;                   // [8192][256]
  float* attn_out = ctx_out + (size_t)NX_ * OUT_;    // [8192][8192]

  ushort* fh   = (ushort*)d_ws;
  ushort* fl   = fh + (size_t)NF_ * FS_;
  ushort* hh   = fl + (size_t)NF_ * FS_;
  ushort* hl   = hh + (size_t)NX_ * OUT_;
  ushort* Qh   = hl + (size_t)NX_ * OUT_;
  ushort* Ql   = Qh + (size_t)NX_ * DQ_;
  ushort* Kh   = Ql + (size_t)NX_ * DQ_;
  ushort* Kl   = Kh + (size_t)NF_ * DQ_;
  ushort* VT   = Kl + (size_t)NF_ * DQ_;
  ushort* WhTh = VT + (size_t)OUT_ * NX_;
  ushort* WhTl = WhTh + 32768;
  ushort* WkTh = WhTl + 32768;
  ushort* WkTl = WkTh + 65536;
  ushort* WvTh = WkTl + 65536;
  ushort* WvTl = WvTh + 131072;
  int*    rng  = (int*)(WvTl + 131072);

  hipLaunchKernelGGL(ranges_kernel, dim3(1), dim3(64), 0, stream, xbt, fb, rng);
  hipLaunchKernelGGL(wprep_kernel, dim3(896), dim3(256), 0, stream,
                     Wh, Wk, Wv, WhTh, WhTl, WkTh, WkTl, WvTh, WvTl);
  hipLaunchKernelGGL(prep_split, dim3(2048), dim3(256), 0, stream,
                     f, h, fh, fl, hh, hl);
  hipLaunchKernelGGL(gemm_all, dim3(1024), dim3(256), 0, stream,
                     fh, fl, hh, hl, WhTh, WhTl, WkTh, WkTl, WvTh,
                     Qh, Ql, Kh, Kl, VT);
  hipLaunchKernelGGL(fused_attn, dim3(NX_ / 16), dim3(512), 0, stream,
                     Qh, Ql, Kh, Kl, VT, xbt, rng, attn_out, ctx_out);
}